// Round 2
// baseline (29342.599 us; speedup 1.0000x reference)
//
#include <hip/hip_runtime.h>
#include <cstdint>
#include <cstddef>

#define T_SEQ 4096
#define HSZ   512
#define NGATE 2048   // 4*HSZ
#define DIN   1024
#define NBC   32     // blocks per chain (= CUs per XCD)
#define HBC   16     // h-elements per block
#define S_SLOT 16    // exchange slots (power of 2)
#define CH0   68     // skewed LDS chunk stride, 64-col chunks (L0)
#define CH1   132    // skewed LDS chunk stride, 128-col chunks (L1)

typedef unsigned long long u64;
typedef unsigned int u32;

// agent-scope (LLC) exchange ops — correct across XCDs
__device__ __forceinline__ u64 exld(const u64* p) {
  return __hip_atomic_load(p, __ATOMIC_RELAXED, __HIP_MEMORY_SCOPE_AGENT);
}
__device__ __forceinline__ void exst(u64* p, u64 v) {
  __hip_atomic_store(p, v, __ATOMIC_RELAXED, __HIP_MEMORY_SCOPE_AGENT);
}
__device__ __forceinline__ int pgld(const u32* p) {
  return (int)__hip_atomic_load(p, __ATOMIC_RELAXED, __HIP_MEMORY_SCOPE_AGENT);
}
__device__ __forceinline__ void pgst(u32* p, u32 v) {
  __hip_atomic_store(p, v, __ATOMIC_RELAXED, __HIP_MEMORY_SCOPE_AGENT);
}

// fast path: sc0 load bypasses L1, hits the XCD-local L2 (coherent only same-XCD)
__device__ __forceinline__ u64 l2ld(const u64* p) {
  u64 v;
  asm volatile("global_load_dwordx2 %0, %1, off sc0\n\ts_waitcnt vmcnt(0)"
               : "=v"(v) : "v"(p) : "memory");
  return v;
}
// fast publish: plain store -> local L2 (L1 is write-through)
__device__ __forceinline__ void l2st(u64* p, u64 v) {
  asm volatile("global_store_dwordx2 %0, %1, off" :: "v"(p), "v"(v) : "memory");
}

// fast activations
__device__ __forceinline__ float frcp(float x) { return __builtin_amdgcn_rcpf(x); }
__device__ __forceinline__ float fsig(float x) { return frcp(1.f + __expf(-x)); }
__device__ __forceinline__ float ftnh(float x) { return 1.f - 2.f * frcp(1.f + __expf(2.f * x)); }

// ---------------- init: zero exchange slots (epoch0 == h_0 == 0) + progress flags ----------------
// ex0 and ex1 are contiguous: total 2 arrays * 2 dirs * S_SLOT * HSZ u64
__global__ void init_sync_kernel(u64* ex, u32* prog) {
  const int tid = blockIdx.x * blockDim.x + threadIdx.x;
  if (tid < 2 * 2 * S_SLOT * HSZ) exst(&ex[tid], 0ull);
  if (tid < 4 * NBC) pgst(&prog[tid], 0u);
}

// ---------------- fp32 GEMM with bias: P[t,r] = sum_k X[t,k]*W[r,k] + bi[r] + bh[r] ----------------
__global__ __launch_bounds__(256, 2)
void gemm_bias_kernel(const float* __restrict__ Xf, const float* __restrict__ Xb,
                      const float* __restrict__ Wf, const float* __restrict__ Wb,
                      const float* __restrict__ bif, const float* __restrict__ bhf,
                      const float* __restrict__ bib, const float* __restrict__ bhb,
                      float* __restrict__ Pf, float* __restrict__ Pb, int K)
{
  const int dir = blockIdx.z;
  const float* X  = dir ? Xb  : Xf;
  const float* W  = dir ? Wb  : Wf;
  const float* bi = dir ? bib : bif;
  const float* bh = dir ? bhb : bhf;
  float* P        = dir ? Pb  : Pf;

  const int m0 = blockIdx.x * 128;
  const int n0 = blockIdx.y * 128;
  const int tid = threadIdx.x;
  const int lr = tid >> 1;
  const int lk = (tid & 1) * 8;

  __shared__ float As[16*128];
  __shared__ float Bs[16*128];

  float acc[8][8];
  #pragma unroll
  for (int i = 0; i < 8; ++i)
    #pragma unroll
    for (int j = 0; j < 8; ++j) acc[i][j] = 0.f;

  for (int k0 = 0; k0 < K; k0 += 16) {
    const float4 a0 = *(const float4*)(X + (size_t)(m0+lr)*K + k0 + lk);
    const float4 a1 = *(const float4*)(X + (size_t)(m0+lr)*K + k0 + lk + 4);
    const float4 b0 = *(const float4*)(W + (size_t)(n0+lr)*K + k0 + lk);
    const float4 b1 = *(const float4*)(W + (size_t)(n0+lr)*K + k0 + lk + 4);
    __syncthreads();
    As[(lk+0)*128+lr]=a0.x; As[(lk+1)*128+lr]=a0.y; As[(lk+2)*128+lr]=a0.z; As[(lk+3)*128+lr]=a0.w;
    As[(lk+4)*128+lr]=a1.x; As[(lk+5)*128+lr]=a1.y; As[(lk+6)*128+lr]=a1.z; As[(lk+7)*128+lr]=a1.w;
    Bs[(lk+0)*128+lr]=b0.x; Bs[(lk+1)*128+lr]=b0.y; Bs[(lk+2)*128+lr]=b0.z; Bs[(lk+3)*128+lr]=b0.w;
    Bs[(lk+4)*128+lr]=b1.x; Bs[(lk+5)*128+lr]=b1.y; Bs[(lk+6)*128+lr]=b1.z; Bs[(lk+7)*128+lr]=b1.w;
    __syncthreads();
    #pragma unroll
    for (int kk = 0; kk < 16; ++kk) {
      const float4 A0 = *(const float4*)(As + kk*128 + (tid&15)*8);
      const float4 A1 = *(const float4*)(As + kk*128 + (tid&15)*8 + 4);
      const float4 B0 = *(const float4*)(Bs + kk*128 + (tid>>4)*8);
      const float4 B1 = *(const float4*)(Bs + kk*128 + (tid>>4)*8 + 4);
      const float av[8] = {A0.x,A0.y,A0.z,A0.w,A1.x,A1.y,A1.z,A1.w};
      const float bv[8] = {B0.x,B0.y,B0.z,B0.w,B1.x,B1.y,B1.z,B1.w};
      #pragma unroll
      for (int i = 0; i < 8; ++i)
        #pragma unroll
        for (int j = 0; j < 8; ++j) acc[i][j] += av[i]*bv[j];
    }
  }
  const int tm = m0 + (tid&15)*8;
  const int tn = n0 + (tid>>4)*8;
  #pragma unroll
  for (int i = 0; i < 8; ++i) {
    #pragma unroll
    for (int j = 0; j < 8; ++j) {
      const int n = tn + j;
      P[(size_t)(tm+i)*NGATE + n] = acc[i][j] + bi[n] + bh[n];
    }
  }
}

// ---------------- fused persistent recurrence: XCD-local exchange ----------------
// 256 blocks x 512 threads. chain = bid%8 (0:L0f 1:L0b 2:L1f 3:L1b, 4-7 exit), b = bid>>3.
// Assumes round-robin block->XCD dispatch so a chain's 32 blocks share one XCD:
//   h publish = plain store (local L2) + agent store (LLC); h poll = sc0 load (local L2).
// Correctness does NOT depend on the mapping: per-thread sticky fallback escalates
// to agent-scope polling after 1536 stale iterations (perf-only downside).
// 16 slots; guard checked every 8 steps with loads issued early (overlapped).
__global__ __launch_bounds__(512, 2)
void fused_recur_kernel(const float* __restrict__ Whh0_f, const float* __restrict__ Whh0_b,
                        const float* __restrict__ Wih1_f, const float* __restrict__ Whh1_f,
                        const float* __restrict__ bih1_f, const float* __restrict__ bhh1_f,
                        const float* __restrict__ Wih1_b, const float* __restrict__ Whh1_b,
                        const float* __restrict__ bih1_b, const float* __restrict__ bhh1_b,
                        const float* __restrict__ P_f, const float* __restrict__ P_b,
                        u64* ex0, u64* ex1, u32* prog0, u32* prog1,
                        float* __restrict__ out)
{
  const int xcd = blockIdx.x & 7;
  const int b   = blockIdx.x >> 3;
  if (xcd >= 4 || b >= NBC) return;
  const int dir  = xcd & 1;
  const int tid  = threadIdx.x;
  const int lane = tid & 63;
  const int wv   = tid >> 6;

  __shared__ float xh[2][8*CH1];   // double-buffered skewed chunks (sized for L1)

  // lane -> (gate g, element e, col-chunk cc); 4 gates of an element are adjacent lanes
  const int g  = lane & 3;
  const int cc = lane >> 3;                    // 0..7
  const int e  = wv*2 + ((lane >> 2) & 1);     // 0..15
  const int grow = g*HSZ + b*HBC + e;          // global gate-row
  const bool red0 = (cc == 0);
  const bool act  = red0 && (g == 0);

  if (xcd < 2) {
    // ---------------- layer 0 ----------------
    const float* Whh = dir ? Whh0_b : Whh0_f;
    const float* P   = dir ? P_b    : P_f;
    u64* exS  = ex0 + (size_t)dir*S_SLOT*HSZ;
    u32* prS  = prog0 + dir*NBC;
    u32* prL1 = prog1 + dir*NBC;

    float4 w[16];   // 64 cols per lane
    {
      const float4* wp = (const float4*)(Whh + (size_t)grow*HSZ + cc*64);
      #pragma unroll
      for (int j = 0; j < 16; ++j) w[j] = wp[j];
    }

    float creg = 0.f;
    float pv = 0.f;
    if (red0) pv = P[(size_t)(dir ? (T_SEQ-1) : 0)*NGATE + grow];
    bool fastH = true;

    for (int t = 0; t < T_SEQ; ++t) {
      // guard loads issued early (every 8 steps; verified after barrier)
      int gv = 0x7fffffff;
      if ((t & 7) == 0) {
        if (tid >= 64 && tid < 96)       gv = pgld(&prS[tid-64]);
        else if (tid >= 96 && tid < 128) gv = pgld(&prL1[tid-96]);
      }
      // poll h_t (fast local-L2 path with sticky agent fallback)
      {
        const u64* sp = exS + (size_t)(t & (S_SLOT-1))*HSZ + tid;
        u64 v = fastH ? l2ld(sp) : exld(sp);
        int it = 0;
        while ((u32)(v >> 32) != (u32)t) {
          if (fastH && ++it > 1536) fastH = false;
          v = fastH ? l2ld(sp) : exld(sp);
        }
        xh[t & 1][(tid>>6)*CH0 + (tid & 63)] = __uint_as_float((u32)v);
      }
      __syncthreads();
      if (tid == 0) pgst(&prS[b], (u32)(t+1));   // reads for step t done
      // next-step P prefetch (overlaps matvec)
      float pvn = 0.f;
      if (red0 && t+1 < T_SEQ) pvn = P[(size_t)(dir ? (T_SEQ-2-t) : (t+1))*NGATE + grow];
      // guard verify (rarely spins; ordered before epoch t+2 publish by next barrier)
      if (gv < t-6) {
        const u32* gp = (tid < 96) ? &prS[tid-64] : &prL1[tid-96];
        while (pgld(gp) < t-6) {}
      }
      // matvec: 16 float4 broadcast reads from LDS chunk cc
      const float4* h4 = (const float4*)(xh[t & 1] + cc*CH0);
      float a0=0.f, a1=0.f, a2=0.f, a3=0.f;
      #pragma unroll
      for (int j = 0; j < 16; j += 4) {
        const float4 h0=h4[j], h1=h4[j+1], h2=h4[j+2], h3=h4[j+3];
        a0 += w[j].x*h0.x   + w[j].y*h0.y   + w[j].z*h0.z   + w[j].w*h0.w;
        a1 += w[j+1].x*h1.x + w[j+1].y*h1.y + w[j+1].z*h1.z + w[j+1].w*h1.w;
        a2 += w[j+2].x*h2.x + w[j+2].y*h2.y + w[j+2].z*h2.z + w[j+2].w*h2.w;
        a3 += w[j+3].x*h3.x + w[j+3].y*h3.y + w[j+3].z*h3.z + w[j+3].w*h3.w;
      }
      float acc = (a0+a1)+(a2+a3);
      acc += __shfl_xor(acc, 8);
      acc += __shfl_xor(acc, 16);
      acc += __shfl_xor(acc, 32);
      const float val = acc + pv;
      pv = pvn;
      // parallel activation on the 4 gate lanes, then gather
      const float av = (g == 2) ? ftnh(val) : fsig(val);
      const float f1 = __shfl_xor(av, 1);
      const float f2 = __shfl_xor(av, 2);
      const float f3 = __shfl_xor(av, 3);
      if (act) {
        creg = f1*creg + av*f2;          // f_s*c + i_s*tanh(g)
        const float hnew = f3*ftnh(creg);
        const int hidx = b*HBC + e;
        u64* dst = exS + (size_t)((t+1) & (S_SLOT-1))*HSZ + hidx;
        const u64 pkt = ((u64)(u32)(t+1) << 32) | (u64)__float_as_uint(hnew);
        l2st(dst, pkt);    // fast local-L2 copy (same-XCD readers)
        exst(dst, pkt);    // LLC copy (L1 x-readers + sticky fallback)
        if (t == T_SEQ-1) {
          out[dir*HSZ + hidx]        = creg;   // cell_memories layer 0
          out[2048 + dir*HSZ + hidx] = hnew;   // hidden_states layer 0
        }
      }
    }
  } else {
    // ---------------- layer 1 ----------------
    const float* Wih = dir ? Wih1_b : Wih1_f;
    const float* Whh = dir ? Whh1_b : Whh1_f;
    const float* biv = dir ? bih1_b : bih1_f;
    const float* bhv = dir ? bhh1_b : bhh1_f;
    u64* exX = ex0 + (size_t)dir*S_SLOT*HSZ;   // x source = layer-0 outputs (cross-XCD)
    u64* exS = ex1 + (size_t)dir*S_SLOT*HSZ;   // self h exchange (local XCD)
    u32* prS = prog1 + dir*NBC;

    float4 w[32];   // 128 cols per lane: cc<4 -> Wih/x, cc>=4 -> Whh/h
    {
      const float* wsrc = (cc < 4) ? (Wih + (size_t)grow*HSZ + cc*128)
                                   : (Whh + (size_t)grow*HSZ + (cc-4)*128);
      const float4* wp = (const float4*)wsrc;
      #pragma unroll
      for (int j = 0; j < 32; ++j) w[j] = wp[j];
    }
    const float brow = red0 ? (biv[grow] + bhv[grow]) : 0.f;

    float creg = 0.f;
    bool fastH = true;
    u64 xpf = exld(exX + (size_t)(1 & (S_SLOT-1))*HSZ + tid);   // prefetch x epoch 1

    for (int t = 0; t < T_SEQ; ++t) {
      int gv = 0x7fffffff;
      if ((t & 7) == 0 && tid >= 64 && tid < 96) gv = pgld(&prS[tid-64]);
      // poll own h (fast path) + x (prefetched agent load, poll fallback)
      {
        const u64* ph = exS + (size_t)(t & (S_SLOT-1))*HSZ + tid;
        const u64* px = exX + (size_t)((t+1) & (S_SLOT-1))*HSZ + tid;
        u64 vx = xpf; bool ox = ((u32)(vx >> 32) == (u32)(t+1));
        u64 vh = fastH ? l2ld(ph) : exld(ph);
        bool oh = ((u32)(vh >> 32) == (u32)t);
        int it = 0;
        while (!(ox && oh)) {
          if (!ox) { u64 v2 = exld(px); if ((u32)(v2>>32) == (u32)(t+1)) { vx = v2; ox = true; } }
          if (!oh) {
            if (fastH && ++it > 1536) fastH = false;
            u64 v2 = fastH ? l2ld(ph) : exld(ph);
            if ((u32)(v2>>32) == (u32)t) { vh = v2; oh = true; }
          }
        }
        float* xb = xh[t & 1];
        xb[(tid>>7)*CH1 + (tid & 127)]       = __uint_as_float((u32)vx);   // chunks 0..3 (x)
        xb[(4 + (tid>>7))*CH1 + (tid & 127)] = __uint_as_float((u32)vh);   // chunks 4..7 (h)
      }
      __syncthreads();
      if (tid == 0) pgst(&prS[b], (u32)(t+1));
      xpf = exld(exX + (size_t)((t+2) & (S_SLOT-1))*HSZ + tid);   // prefetch next x (checked next step)
      if (gv < t-6) { while (pgld(&prS[tid-64]) < t-6) {} }
      // matvec: 32 float4 broadcast reads from LDS chunk cc
      const float4* h4 = (const float4*)(xh[t & 1] + cc*CH1);
      float a0=0.f, a1=0.f, a2=0.f, a3=0.f;
      #pragma unroll
      for (int j = 0; j < 32; j += 4) {
        const float4 h0=h4[j], h1=h4[j+1], h2=h4[j+2], h3=h4[j+3];
        a0 += w[j].x*h0.x   + w[j].y*h0.y   + w[j].z*h0.z   + w[j].w*h0.w;
        a1 += w[j+1].x*h1.x + w[j+1].y*h1.y + w[j+1].z*h1.z + w[j+1].w*h1.w;
        a2 += w[j+2].x*h2.x + w[j+2].y*h2.y + w[j+2].z*h2.z + w[j+2].w*h2.w;
        a3 += w[j+3].x*h3.x + w[j+3].y*h3.y + w[j+3].z*h3.z + w[j+3].w*h3.w;
      }
      float acc = (a0+a1)+(a2+a3);
      acc += __shfl_xor(acc, 8);
      acc += __shfl_xor(acc, 16);
      acc += __shfl_xor(acc, 32);
      const float val = acc + brow;
      const float av = (g == 2) ? ftnh(val) : fsig(val);
      const float f1 = __shfl_xor(av, 1);
      const float f2 = __shfl_xor(av, 2);
      const float f3 = __shfl_xor(av, 3);
      if (act) {
        creg = f1*creg + av*f2;
        const float hnew = f3*ftnh(creg);
        const int hidx = b*HBC + e;
        u64* dst = exS + (size_t)((t+1) & (S_SLOT-1))*HSZ + hidx;
        const u64 pkt = ((u64)(u32)(t+1) << 32) | (u64)__float_as_uint(hnew);
        l2st(dst, pkt);
        exst(dst, pkt);
        const int trow = dir ? (T_SEQ-1-t) : t;
        out[4096 + (size_t)trow*1024 + dir*HSZ + hidx] = hnew;   // top-layer outputs
        if (t == T_SEQ-1) {
          out[1024 + dir*HSZ + hidx]        = creg;   // cell_memories layer 1
          out[2048 + 1024 + dir*HSZ + hidx] = hnew;   // hidden_states layer 1
        }
      }
    }
  }
}

// ---------------- launch ----------------
extern "C" void kernel_launch(void* const* d_in, const int* in_sizes, int n_in,
                              void* d_out, int out_size, void* d_ws, size_t ws_size,
                              hipStream_t stream)
{
  const float* emb   = (const float*)d_in[0];
  const float* fWih0 = (const float*)d_in[1];
  const float* fWhh0 = (const float*)d_in[2];
  const float* fbih0 = (const float*)d_in[3];
  const float* fbhh0 = (const float*)d_in[4];
  const float* fWih1 = (const float*)d_in[5];
  const float* fWhh1 = (const float*)d_in[6];
  const float* fbih1 = (const float*)d_in[7];
  const float* fbhh1 = (const float*)d_in[8];
  const float* bWih0 = (const float*)d_in[9];
  const float* bWhh0 = (const float*)d_in[10];
  const float* bbih0 = (const float*)d_in[11];
  const float* bbhh0 = (const float*)d_in[12];
  const float* bWih1 = (const float*)d_in[13];
  const float* bWhh1 = (const float*)d_in[14];
  const float* bbih1 = (const float*)d_in[15];
  const float* bbhh1 = (const float*)d_in[16];
  float* out = (float*)d_out;

  // workspace: P[2][4096][2048] fp32 (67 MB), ex0/ex1 [2][S_SLOT][512] u64 each, progress flags
  float* P_f = (float*)d_ws;
  float* P_b = P_f + (size_t)T_SEQ*NGATE;
  u64*   ex0 = (u64*)(P_b + (size_t)T_SEQ*NGATE);
  u64*   ex1 = ex0 + 2*S_SLOT*HSZ;
  u32*   prog0 = (u32*)(ex1 + 2*S_SLOT*HSZ);
  u32*   prog1 = prog0 + 2*NBC;

  init_sync_kernel<<<32, 1024, 0, stream>>>(ex0, prog0);

  // layer-0 input projections for both directions (bwd reads P reversed in time)
  gemm_bias_kernel<<<dim3(32,16,2), 256, 0, stream>>>(
      emb, emb, fWih0, bWih0, fbih0, fbhh0, bbih0, bbhh0, P_f, P_b, DIN);

  // fused pipelined recurrence: chains pinned per-XCD by bid%8 (perf assumption only)
  fused_recur_kernel<<<256, 512, 0, stream>>>(
      fWhh0, bWhh0,
      fWih1, fWhh1, fbih1, fbhh1,
      bWih1, bWhh1, bbih1, bbhh1,
      P_f, P_b, ex0, ex1, prog0, prog1, out);
}

// Round 4
// 7916.187 us; speedup vs baseline: 3.7067x; 3.7067x over previous
//
#include <hip/hip_runtime.h>
#include <cstdint>
#include <cstddef>

#define T_SEQ 4096
#define HSZ   512
#define NGATE 2048   // 4*HSZ
#define DIN   1024
#define NB0   16     // layer-0 blocks per direction
#define HB0   32     // h-elements per layer-0 block
#define NB1   32     // layer-1 blocks per direction
#define HB1   16     // h-elements per layer-1 block
#define S_SLOT 16    // exchange ring slots (power of 2)
#define CH    132    // skewed LDS chunk stride (128 + 4)

typedef unsigned long long u64;
typedef unsigned int u32;

__device__ __forceinline__ u64 exld(const u64* p) {
  return __hip_atomic_load(p, __ATOMIC_RELAXED, __HIP_MEMORY_SCOPE_AGENT);
}
__device__ __forceinline__ void exst(u64* p, u64 v) {
  __hip_atomic_store(p, v, __ATOMIC_RELAXED, __HIP_MEMORY_SCOPE_AGENT);
}
__device__ __forceinline__ int pgld(const u32* p) {
  return (int)__hip_atomic_load(p, __ATOMIC_RELAXED, __HIP_MEMORY_SCOPE_AGENT);
}
__device__ __forceinline__ void pgst(u32* p, u32 v) {
  __hip_atomic_store(p, v, __ATOMIC_RELAXED, __HIP_MEMORY_SCOPE_AGENT);
}

// fast activations: v_rcp + v_exp (no div sequences, no libm tanh)
__device__ __forceinline__ float frcp(float x) { return __builtin_amdgcn_rcpf(x); }
__device__ __forceinline__ float fsig(float x) { return frcp(1.f + __expf(-x)); }
__device__ __forceinline__ float ftnh(float x) { return 1.f - 2.f * frcp(1.f + __expf(2.f * x)); }

// ---------------- init: zero exchange slots (epoch0 == h_0 == 0) + progress flags ----------------
__global__ void init_sync_kernel(u64* ex, u32* prog) {
  const int tid = blockIdx.x * blockDim.x + threadIdx.x;
  if (tid < 2 * 2 * S_SLOT * HSZ) exst(&ex[tid], 0ull);
  if (tid < 2 * (NB0 + NB1)) pgst(&prog[tid], 0u);
}

// ---------------- fp32 GEMM with bias: P[t,r] = sum_k X[t,k]*W[r,k] + bi[r] + bh[r] ----------------
__global__ __launch_bounds__(256, 2)
void gemm_bias_kernel(const float* __restrict__ Xf, const float* __restrict__ Xb,
                      const float* __restrict__ Wf, const float* __restrict__ Wb,
                      const float* __restrict__ bif, const float* __restrict__ bhf,
                      const float* __restrict__ bib, const float* __restrict__ bhb,
                      float* __restrict__ Pf, float* __restrict__ Pb, int K)
{
  const int dir = blockIdx.z;
  const float* X  = dir ? Xb  : Xf;
  const float* W  = dir ? Wb  : Wf;
  const float* bi = dir ? bib : bif;
  const float* bh = dir ? bhb : bhf;
  float* P        = dir ? Pb  : Pf;

  const int m0 = blockIdx.x * 128;
  const int n0 = blockIdx.y * 128;
  const int tid = threadIdx.x;
  const int lr = tid >> 1;
  const int lk = (tid & 1) * 8;

  __shared__ float As[16*128];
  __shared__ float Bs[16*128];

  float acc[8][8];
  #pragma unroll
  for (int i = 0; i < 8; ++i)
    #pragma unroll
    for (int j = 0; j < 8; ++j) acc[i][j] = 0.f;

  for (int k0 = 0; k0 < K; k0 += 16) {
    const float4 a0 = *(const float4*)(X + (size_t)(m0+lr)*K + k0 + lk);
    const float4 a1 = *(const float4*)(X + (size_t)(m0+lr)*K + k0 + lk + 4);
    const float4 b0 = *(const float4*)(W + (size_t)(n0+lr)*K + k0 + lk);
    const float4 b1 = *(const float4*)(W + (size_t)(n0+lr)*K + k0 + lk + 4);
    __syncthreads();
    As[(lk+0)*128+lr]=a0.x; As[(lk+1)*128+lr]=a0.y; As[(lk+2)*128+lr]=a0.z; As[(lk+3)*128+lr]=a0.w;
    As[(lk+4)*128+lr]=a1.x; As[(lk+5)*128+lr]=a1.y; As[(lk+6)*128+lr]=a1.z; As[(lk+7)*128+lr]=a1.w;
    Bs[(lk+0)*128+lr]=b0.x; Bs[(lk+1)*128+lr]=b0.y; Bs[(lk+2)*128+lr]=b0.z; Bs[(lk+3)*128+lr]=b0.w;
    Bs[(lk+4)*128+lr]=b1.x; Bs[(lk+5)*128+lr]=b1.y; Bs[(lk+6)*128+lr]=b1.z; Bs[(lk+7)*128+lr]=b1.w;
    __syncthreads();
    #pragma unroll
    for (int kk = 0; kk < 16; ++kk) {
      const float4 A0 = *(const float4*)(As + kk*128 + (tid&15)*8);
      const float4 A1 = *(const float4*)(As + kk*128 + (tid&15)*8 + 4);
      const float4 B0 = *(const float4*)(Bs + kk*128 + (tid>>4)*8);
      const float4 B1 = *(const float4*)(Bs + kk*128 + (tid>>4)*8 + 4);
      const float av[8] = {A0.x,A0.y,A0.z,A0.w,A1.x,A1.y,A1.z,A1.w};
      const float bv[8] = {B0.x,B0.y,B0.z,B0.w,B1.x,B1.y,B1.z,B1.w};
      #pragma unroll
      for (int i = 0; i < 8; ++i)
        #pragma unroll
        for (int j = 0; j < 8; ++j) acc[i][j] += av[i]*bv[j];
    }
  }
  const int tm = m0 + (tid&15)*8;
  const int tn = n0 + (tid>>4)*8;
  #pragma unroll
  for (int i = 0; i < 8; ++i) {
    #pragma unroll
    for (int j = 0; j < 8; ++j) {
      const int n = tn + j;
      P[(size_t)(tm+i)*NGATE + n] = acc[i][j] + bi[n] + bh[n];
    }
  }
}

// ---------------- fused persistent recurrence: both layers, both directions, pipelined ----------------
// blocks [0,16): L0 fwd   [16,32): L0 bwd   [32,64): L1 fwd   [64,96): L1 bwd
// Exchange: u64 = (epoch<<32)|float_bits into slot epoch&(S_SLOT-1), agent scope (LLC).
// 16-slot ring + guard (every 8 steps, require consumers >= t-4) gives ~12 steps of
// pipeline elasticity: L1's natural 1-step lag and flag-propagation jitter no longer
// stall L0's writers (round-0's 4-slot/t-2/every-step guard had <=1 step margin).
__global__ __launch_bounds__(512, 2)
void fused_recur_kernel(const float* __restrict__ Whh0_f, const float* __restrict__ Whh0_b,
                        const float* __restrict__ Wih1_f, const float* __restrict__ Whh1_f,
                        const float* __restrict__ bih1_f, const float* __restrict__ bhh1_f,
                        const float* __restrict__ Wih1_b, const float* __restrict__ Whh1_b,
                        const float* __restrict__ bih1_b, const float* __restrict__ bhh1_b,
                        const float* __restrict__ P_f, const float* __restrict__ P_b,
                        u64* ex0, u64* ex1, u32* prog0, u32* prog1,
                        float* __restrict__ out)
{
  const int bx  = blockIdx.x;
  const int tid = threadIdx.x;
  const int lane = tid & 63;
  const int wv   = tid >> 6;

  __shared__ float xh[8*CH];     // skewed chunks: bank-conflict-free wave-uniform b128 reads
  __shared__ float gates[128];

  if (bx < 2*NB0) {
    // ---------------- layer 0 ----------------
    const int dir = (bx >= NB0) ? 1 : 0;
    const int b   = bx - dir*NB0;
    const float* Whh = dir ? Whh0_b : Whh0_f;
    const float* P   = dir ? P_b    : P_f;
    u64* exS   = ex0 + (size_t)dir*S_SLOT*HSZ;   // self exchange (also read by layer 1)
    u32* prS   = prog0 + dir*NB0;
    u32* prL1  = prog1 + dir*NB1;

    const int cc        = lane >> 4;             // col chunk 0..3
    const int row_local = wv*16 + (lane & 15);   // 0..127
    const int gate = row_local >> 5, k = row_local & 31;
    const int grow = gate*HSZ + b*HB0 + k;
    const bool wr  = (lane >> 4) == 0;           // row-sum writer lanes

    float4 w[32];
    {
      const float4* wp = (const float4*)(Whh + (size_t)grow*HSZ + cc*128);
      #pragma unroll
      for (int j = 0; j < 32; ++j) w[j] = wp[j];
    }

    float creg = 0.f;
    float pv = 0.f;
    if (wr) pv = P[(size_t)(dir ? (T_SEQ-1) : 0)*NGATE + grow];

    for (int t = 0; t < T_SEQ; ++t) {
      // slot-overwrite guard, every 8 steps (consumers: L0 peers + L1 blocks of this dir)
      if ((t & 7) == 0) {
        if (tid >= 64 && tid < 64+NB0)       { while (pgld(&prS[tid-64])  < t-4) {} }
        else if (tid >= 96 && tid < 96+NB1)  { while (pgld(&prL1[tid-96]) < t-4) {} }
      }
      // poll h_t directly from exchange (epoch == t), stage to skewed LDS
      {
        const u64* sp = exS + (size_t)(t & (S_SLOT-1))*HSZ + tid;
        u64 v;
        do { v = exld(sp); } while ((u32)(v >> 32) != (u32)t);
        xh[(tid>>7)*CH + (tid & 127)] = __uint_as_float((u32)v);
      }
      __syncthreads();
      if (tid == 0) pgst(&prS[b], (u32)(t+1));   // epoch-t reads complete
      // next-step P prefetch (one step of miss-hiding)
      float pvn = 0.f;
      if (wr && t+1 < T_SEQ) pvn = P[(size_t)(dir ? (T_SEQ-2-t) : (t+1))*NGATE + grow];
      // matvec: lane covers 128 cols (chunk cc) of its row
      const float4* h4 = (const float4*)(xh + cc*CH);
      float a0=0.f, a1=0.f, a2=0.f, a3=0.f;
      #pragma unroll
      for (int j = 0; j < 32; j += 4) {
        const float4 h0 = h4[j], h1 = h4[j+1], h2 = h4[j+2], h3 = h4[j+3];
        a0 += w[j].x*h0.x   + w[j].y*h0.y   + w[j].z*h0.z   + w[j].w*h0.w;
        a1 += w[j+1].x*h1.x + w[j+1].y*h1.y + w[j+1].z*h1.z + w[j+1].w*h1.w;
        a2 += w[j+2].x*h2.x + w[j+2].y*h2.y + w[j+2].z*h2.z + w[j+2].w*h2.w;
        a3 += w[j+3].x*h3.x + w[j+3].y*h3.y + w[j+3].z*h3.z + w[j+3].w*h3.w;
      }
      float acc = (a0+a1)+(a2+a3);
      acc += __shfl_xor(acc, 16);
      acc += __shfl_xor(acc, 32);
      if (wr) gates[row_local] = acc + pv;
      pv = pvn;
      __syncthreads();
      if (tid < HB0) {
        const float ig = gates[tid], fg = gates[32+tid], gg = gates[64+tid], og = gates[96+tid];
        const float i_s = fsig(ig);
        const float f_s = fsig(fg);
        const float o_s = fsig(og);
        creg = f_s*creg + i_s*ftnh(gg);
        const float hnew = o_s*ftnh(creg);
        const int hidx = b*HB0 + tid;
        const u64 pkt = ((u64)(u32)(t+1) << 32) | (u64)__float_as_uint(hnew);
        exst(exS + (size_t)((t+1) & (S_SLOT-1))*HSZ + hidx, pkt);
        if (t == T_SEQ-1) {
          out[dir*HSZ + hidx]        = creg;   // cell_memories layer 0
          out[2048 + dir*HSZ + hidx] = hnew;   // hidden_states layer 0
        }
      }
    }
  } else {
    // ---------------- layer 1 ----------------
    const int r   = bx - 2*NB0;
    const int dir = (r >= NB1) ? 1 : 0;
    const int b   = r - dir*NB1;
    const float* Wih = dir ? Wih1_b : Wih1_f;
    const float* Whh = dir ? Whh1_b : Whh1_f;
    const float* bi  = dir ? bih1_b : bih1_f;
    const float* bh  = dir ? bhh1_b : bhh1_f;
    u64* exX = ex0 + (size_t)dir*S_SLOT*HSZ;     // x source = layer-0 outputs
    u64* exS = ex1 + (size_t)dir*S_SLOT*HSZ;     // self h exchange
    u32* prS = prog1 + dir*NB1;

    const int sub       = lane >> 3;             // 0..7 col chunk (0-3: Wih/x, 4-7: Whh/h)
    const int row_local = wv*8 + (lane & 7);     // 0..63
    const int gate = row_local >> 4, k = row_local & 15;
    const int grow = gate*HSZ + b*HB1 + k;
    const bool wr  = (lane >> 3) == 0;

    float4 w[32];
    {
      const float* wsrc = (sub < 4) ? (Wih + (size_t)grow*HSZ + sub*128)
                                    : (Whh + (size_t)grow*HSZ + (sub-4)*128);
      const float4* wp = (const float4*)wsrc;
      #pragma unroll
      for (int j = 0; j < 32; ++j) w[j] = wp[j];
    }
    float brow = 0.f;
    if (wr) brow = bi[grow] + bh[grow];

    float creg = 0.f;
    u64 xpf = exld(exX + (size_t)(1 & (S_SLOT-1))*HSZ + tid);   // prefetch x epoch 1

    for (int t = 0; t < T_SEQ; ++t) {
      // slot-overwrite guard, every 8 steps (consumers of ex1: L1 peers of this dir)
      if ((t & 7) == 0 && tid >= 64 && tid < 64+NB1) { while (pgld(&prS[tid-64]) < t-4) {} }
      // poll x_t (layer-0 publish, epoch t+1; usually satisfied by prefetch) and own h_t (epoch t)
      {
        const u64* px = exX + (size_t)((t+1) & (S_SLOT-1))*HSZ + tid;
        const u64* ph = exS + (size_t)(t & (S_SLOT-1))*HSZ + tid;
        u64 vx = xpf; bool okx = ((u32)(vx >> 32) == (u32)(t+1));
        float hv = 0.f; bool okh = false;
        do {
          if (!okx) { u64 v = exld(px); if ((u32)(v >> 32) == (u32)(t+1)) { vx = v; okx = true; } }
          if (!okh) { u64 v = exld(ph); if ((u32)(v >> 32) == (u32)t)     { hv = __uint_as_float((u32)v); okh = true; } }
        } while (!(okx && okh));
        xh[(tid>>7)*CH + (tid & 127)]       = __uint_as_float((u32)vx);   // chunks 0..3
        xh[(4 + (tid>>7))*CH + (tid & 127)] = hv;                         // chunks 4..7
      }
      __syncthreads();
      if (tid == 0) pgst(&prS[b], (u32)(t+1));
      xpf = exld(exX + (size_t)((t+2) & (S_SLOT-1))*HSZ + tid);   // prefetch next x (epoch-tagged)
      const float4* v4 = (const float4*)(xh + sub*CH);
      float a0=0.f, a1=0.f, a2=0.f, a3=0.f;
      #pragma unroll
      for (int j = 0; j < 32; j += 4) {
        const float4 h0 = v4[j], h1 = v4[j+1], h2 = v4[j+2], h3 = v4[j+3];
        a0 += w[j].x*h0.x   + w[j].y*h0.y   + w[j].z*h0.z   + w[j].w*h0.w;
        a1 += w[j+1].x*h1.x + w[j+1].y*h1.y + w[j+1].z*h1.z + w[j+1].w*h1.w;
        a2 += w[j+2].x*h2.x + w[j+2].y*h2.y + w[j+2].z*h2.z + w[j+2].w*h2.w;
        a3 += w[j+3].x*h3.x + w[j+3].y*h3.y + w[j+3].z*h3.z + w[j+3].w*h3.w;
      }
      float acc = (a0+a1)+(a2+a3);
      acc += __shfl_xor(acc, 8);
      acc += __shfl_xor(acc, 16);
      acc += __shfl_xor(acc, 32);
      if (wr) gates[row_local] = acc + brow;
      __syncthreads();
      if (tid < HB1) {
        const float ig = gates[tid], fg = gates[16+tid], gg = gates[32+tid], og = gates[48+tid];
        const float i_s = fsig(ig);
        const float f_s = fsig(fg);
        const float o_s = fsig(og);
        creg = f_s*creg + i_s*ftnh(gg);
        const float hnew = o_s*ftnh(creg);
        const int hidx = b*HB1 + tid;
        const u64 pkt = ((u64)(u32)(t+1) << 32) | (u64)__float_as_uint(hnew);
        exst(exS + (size_t)((t+1) & (S_SLOT-1))*HSZ + hidx, pkt);
        const int trow = dir ? (T_SEQ-1-t) : t;
        out[4096 + (size_t)trow*1024 + dir*HSZ + hidx] = hnew;   // top-layer outputs
        if (t == T_SEQ-1) {
          out[1024 + dir*HSZ + hidx]        = creg;   // cell_memories layer 1
          out[2048 + 1024 + dir*HSZ + hidx] = hnew;   // hidden_states layer 1
        }
      }
    }
  }
}

// ---------------- launch ----------------
extern "C" void kernel_launch(void* const* d_in, const int* in_sizes, int n_in,
                              void* d_out, int out_size, void* d_ws, size_t ws_size,
                              hipStream_t stream)
{
  const float* emb   = (const float*)d_in[0];
  const float* fWih0 = (const float*)d_in[1];
  const float* fWhh0 = (const float*)d_in[2];
  const float* fbih0 = (const float*)d_in[3];
  const float* fbhh0 = (const float*)d_in[4];
  const float* fWih1 = (const float*)d_in[5];
  const float* fWhh1 = (const float*)d_in[6];
  const float* fbih1 = (const float*)d_in[7];
  const float* fbhh1 = (const float*)d_in[8];
  const float* bWih0 = (const float*)d_in[9];
  const float* bWhh0 = (const float*)d_in[10];
  const float* bbih0 = (const float*)d_in[11];
  const float* bbhh0 = (const float*)d_in[12];
  const float* bWih1 = (const float*)d_in[13];
  const float* bWhh1 = (const float*)d_in[14];
  const float* bbih1 = (const float*)d_in[15];
  const float* bbhh1 = (const float*)d_in[16];
  float* out = (float*)d_out;

  // workspace: P[2][4096][2048] fp32 (67 MB), ex0/ex1 [2][S_SLOT][512] u64 each, progress flags
  float* P_f = (float*)d_ws;
  float* P_b = P_f + (size_t)T_SEQ*NGATE;
  u64*   ex0 = (u64*)(P_b + (size_t)T_SEQ*NGATE);
  u64*   ex1 = ex0 + 2*S_SLOT*HSZ;
  u32*   prog0 = (u32*)(ex1 + 2*S_SLOT*HSZ);
  u32*   prog1 = prog0 + 2*NB0;

  init_sync_kernel<<<32, 1024, 0, stream>>>(ex0, prog0);

  // layer-0 input projections for both directions (bwd reads P reversed in time)
  gemm_bias_kernel<<<dim3(32,16,2), 256, 0, stream>>>(
      emb, emb, fWih0, bWih0, fbih0, fbhh0, bbih0, bbhh0, P_f, P_b, DIN);

  // fused pipelined recurrence: L0 fwd/bwd + L1 fwd/bwd in one persistent launch
  fused_recur_kernel<<<96, 512, 0, stream>>>(
      fWhh0, bWhh0,
      fWih1, fWhh1, fbih1, fbhh1,
      bWih1, bWhh1, bbih1, bbhh1,
      P_f, P_b, ex0, ex1, prog0, prog1, out);
}